// Round 2
// baseline (430.420 us; speedup 1.0000x reference)
//
#include <hip/hip_runtime.h>
#include <float.h>

typedef unsigned short u16;
typedef __attribute__((ext_vector_type(8))) short bf16x8;
typedef __attribute__((ext_vector_type(4))) float f32x4;

#define LOG2E 1.4426950408889634f
#define B_ 2
#define S_ 2048
#define D_ 256
#define H_ 8
#define DH_ 32
#define M_ 4096

__device__ __forceinline__ void gload_lds16(const void* g, void* l) {
  __builtin_amdgcn_global_load_lds(
      (const __attribute__((address_space(1))) unsigned int*)g,
      (__attribute__((address_space(3))) unsigned int*)l, 16, 0, 0);
}

__device__ __forceinline__ u16 f2bf(float f) {
  unsigned u = __float_as_uint(f);
  unsigned r = (u + 0x7FFFu + ((u >> 16) & 1u)) >> 16;
  return (u16)r;
}

// ---------------- kernel 1: x (f32) -> bf16 ----------------
__global__ __launch_bounds__(256) void conv_x(const float* __restrict__ x,
                                              u16* __restrict__ xb) {
  int i = (blockIdx.x * 256 + threadIdx.x) * 4;
  float4 v = *(const float4*)(x + i);
  ushort4 o;
  o.x = f2bf(v.x); o.y = f2bf(v.y); o.z = f2bf(v.z); o.w = f2bf(v.w);
  *(ushort4*)(xb + i) = o;
}

// ---------------- kernel 2: weights -> transposed bf16 ----------------
// wt[n][k], n: 0-255 q (scale folded), 256-511 k, 512-767 v, 768-1023 g
// wot[n][k] for Wo
__global__ __launch_bounds__(256) void prep_w(const float* __restrict__ Wq,
                                              const float* __restrict__ Wkv,
                                              const float* __restrict__ Wo,
                                              const float* __restrict__ Wg,
                                              u16* __restrict__ wt,
                                              u16* __restrict__ wot) {
  int t = blockIdx.x * 256 + threadIdx.x;
  const float scale = 0.17677669529663687f;  // DH^-0.5
  if (t < 65536) {                     // Wq: t = k*256+n
    int k = t >> 8, n = t & 255;
    wt[(size_t)n * 256 + k] = f2bf(Wq[t] * scale);
  } else if (t < 196608) {             // Wkv: [256][512]
    int s = t - 65536;
    int k = s >> 9, c = s & 511;
    int n = (c < 256) ? (256 + c) : (512 + (c - 256));
    wt[(size_t)n * 256 + k] = f2bf(Wkv[s]);
  } else if (t < 262144) {             // Wg
    int s = t - 196608;
    int k = s >> 8, n = s & 255;
    wt[(size_t)(768 + n) * 256 + k] = f2bf(Wg[s]);
  } else {                             // Wo
    int s = t - 262144;
    int k = s >> 8, n = s & 255;
    wot[(size_t)n * 256 + k] = f2bf(Wo[s]);
  }
}

// ---------------- kernel 3: projection GEMM 4096x1024x256 ----------------
// 128x128 tile, 4 waves (2x2), 16x16x32 mfma, global_load_lds staging.
// LDS tiles [128 rows][32 k] bf16, 64B rows, XOR swizzle slot ^= (row>>1)&3.
__global__ __launch_bounds__(256) void gemm_proj(
    const u16* __restrict__ xb, const u16* __restrict__ wt,
    const float* __restrict__ bg, u16* __restrict__ qs, u16* __restrict__ kb,
    u16* __restrict__ vt, float* __restrict__ gates) {
  __shared__ u16 lA[128 * 32];
  __shared__ u16 lB[128 * 32];
  const int tid = threadIdx.x, l = tid & 63, w = tid >> 6;
  const int m0 = blockIdx.x * 128, n0 = blockIdx.y * 128;
  const int wm = w >> 1, wn = w & 1;
  f32x4 acc[4][4];
#pragma unroll
  for (int i = 0; i < 4; ++i)
#pragma unroll
    for (int j = 0; j < 4; ++j) acc[i][j] = (f32x4){0.f, 0.f, 0.f, 0.f};

  for (int ks = 0; ks < 8; ++ks) {
#pragma unroll
    for (int i = 0; i < 2; ++i) {
      int slot = i * 256 + tid;
      int row = slot >> 2, sk = slot & 3;
      int sw = sk ^ ((row >> 1) & 3);
      gload_lds16(xb + (size_t)(m0 + row) * 256 + ks * 32 + sw * 8,
                  (char*)lA + slot * 16);
    }
#pragma unroll
    for (int i = 0; i < 2; ++i) {
      int slot = i * 256 + tid;
      int row = slot >> 2, sk = slot & 3;
      int sw = sk ^ ((row >> 1) & 3);
      gload_lds16(wt + (size_t)(n0 + row) * 256 + ks * 32 + sw * 8,
                  (char*)lB + slot * 16);
    }
    __syncthreads();
    bf16x8 af[4], bfr[4];
#pragma unroll
    for (int mi = 0; mi < 4; ++mi) {
      int row = wm * 64 + mi * 16 + (l & 15);
      int koff = ((l >> 4) << 4) ^ (((row >> 1) & 3) << 4);
      af[mi] = *(const bf16x8*)((const char*)lA + row * 64 + koff);
    }
#pragma unroll
    for (int ni = 0; ni < 4; ++ni) {
      int row = wn * 64 + ni * 16 + (l & 15);
      int koff = ((l >> 4) << 4) ^ (((row >> 1) & 3) << 4);
      bfr[ni] = *(const bf16x8*)((const char*)lB + row * 64 + koff);
    }
#pragma unroll
    for (int mi = 0; mi < 4; ++mi)
#pragma unroll
      for (int ni = 0; ni < 4; ++ni)
        acc[mi][ni] = __builtin_amdgcn_mfma_f32_16x16x32_bf16(
            af[mi], bfr[ni], acc[mi][ni], 0, 0, 0);
    __syncthreads();
  }
  // epilogue: C row=(l>>4)*4+r, col=l&15
  const int region = n0 >> 8;  // uniform per block
#pragma unroll
  for (int mi = 0; mi < 4; ++mi)
#pragma unroll
    for (int ni = 0; ni < 4; ++ni) {
      int row = m0 + wm * 64 + mi * 16 + ((l >> 4) << 2);
      int col = n0 + wn * 64 + ni * 16 + (l & 15);
      int c = col & 255;
#pragma unroll
      for (int r = 0; r < 4; ++r) {
        float v = acc[mi][ni][r];
        int rr = row + r;
        int bq = rr >> 11, s = rr & 2047;
        if (region == 0) {
          int h = c >> 5, dh = c & 31;
          qs[((((size_t)bq * 8 + h) * 2048 + s) << 5) + dh] = f2bf(v);
        } else if (region == 1) {
          int h = c >> 5, dh = c & 31;
          kb[((((size_t)bq * 8 + h) * 2048 + s) << 5) + dh] = f2bf(v);
        } else if (region == 2) {
          int h = c >> 5, dh = c & 31;
          vt[((((size_t)bq * 8 + h) * 32 + dh) << 11) + s] = f2bf(v);
        } else {
          float g = 1.f / (1.f + expf(-(v + bg[c])));
          gates[(size_t)rr * 256 + c] = g;
        }
      }
    }
}

// ---------------- kernel 4: flash attention ----------------
// grid (qt=32, h=8, b=2); block 256 = 4 waves, each wave owns 16 q-rows.
// JT=64 j-chunk; K tile [64][32] (swz (row>>1)&3), Vt tile [32][64] (swz row&7),
// P per-wave [16][64] (swz row&7). bias loaded straight into mfma acc.
__global__ __launch_bounds__(256) void attn_fwd(
    const u16* __restrict__ qs, const u16* __restrict__ kb,
    const u16* __restrict__ vt, const float* __restrict__ bias,
    const int* __restrict__ mask, const float* __restrict__ gates,
    u16* __restrict__ ao) {
  __shared__ u16 lK[64 * 32];
  __shared__ u16 lV[32 * 64];
  __shared__ u16 lP[4][16 * 64];
  const int tid = threadIdx.x, l = tid & 63, w = tid >> 6;
  const int qt = blockIdx.x, h = blockIdx.y, b = blockIdx.z;
  const int q0 = qt * 64;
  const size_t bh = (size_t)b * H_ + h;

  const int qrow = q0 + w * 16 + (l & 15);
  bf16x8 qf = *(const bf16x8*)(qs + ((bh * S_ + qrow) << 5) + ((l >> 4) << 3));

  int rowr[4], mi_[4];
  float m_i[4], l_i[4];
  const float* biasrow[4];
  f32x4 acc_o[2];
  acc_o[0] = (f32x4){0.f, 0.f, 0.f, 0.f};
  acc_o[1] = (f32x4){0.f, 0.f, 0.f, 0.f};
#pragma unroll
  for (int r = 0; r < 4; ++r) {
    rowr[r] = q0 + w * 16 + ((l >> 4) << 2) + r;
    mi_[r] = mask[b * S_ + rowr[r]];
    m_i[r] = -FLT_MAX;
    l_i[r] = 0.f;
    biasrow[r] = bias + (bh * S_ + rowr[r]) * (size_t)S_;
  }

  for (int jc = 0; jc < 32; ++jc) {
    const int j0 = jc * 64;
    {  // stage K chunk [64][32]
      int row = tid >> 2, sk = tid & 3;
      int sw = sk ^ ((row >> 1) & 3);
      gload_lds16(kb + ((bh * S_ + j0 + row) << 5) + sw * 8,
                  (char*)lK + tid * 16);
    }
    {  // stage V^T chunk [32][64]
      int dh = tid >> 3, sk = tid & 7;
      int sw = sk ^ (dh & 7);
      gload_lds16(vt + ((bh * 32 + dh) << 11) + j0 + sw * 8,
                  (char*)lV + tid * 16);
    }
    __syncthreads();

    // QK^T with bias+mask pre-loaded into accumulator
    f32x4 sc[4];
#pragma unroll
    for (int cg = 0; cg < 4; ++cg) {
      int j = j0 + cg * 16 + (l & 15);
      int mj = mask[b * S_ + j];
      f32x4 ci;
#pragma unroll
      for (int r = 0; r < 4; ++r) {
        float bv = biasrow[r][j];
        ci[r] = (mi_[r] && mj) ? bv : -FLT_MAX;
      }
      int krow = cg * 16 + (l & 15);
      int koff = ((l >> 4) << 4) ^ (((krow >> 1) & 3) << 4);
      bf16x8 kf = *(const bf16x8*)((const char*)lK + krow * 64 + koff);
      sc[cg] = __builtin_amdgcn_mfma_f32_16x16x32_bf16(qf, kf, ci, 0, 0, 0);
    }

    // online softmax (row = (l>>4)*4+r, cols spread over 16-lane group x 4 cg)
    float corr[4];
#pragma unroll
    for (int r = 0; r < 4; ++r) {
      float v0 = fmaxf(fmaxf(sc[0][r], sc[1][r]), fmaxf(sc[2][r], sc[3][r]));
#pragma unroll
      for (int off = 1; off < 16; off <<= 1) v0 = fmaxf(v0, __shfl_xor(v0, off));
      float mn = fmaxf(m_i[r], v0);
      corr[r] = exp2f((m_i[r] - mn) * LOG2E);
      m_i[r] = mn;
    }
    float rs[4] = {0.f, 0.f, 0.f, 0.f};
#pragma unroll
    for (int cg = 0; cg < 4; ++cg) {
#pragma unroll
      for (int r = 0; r < 4; ++r) {
        float p = exp2f((sc[cg][r] - m_i[r]) * LOG2E);
        rs[r] += p;
        int prow = ((l >> 4) << 2) + r;
        int col = cg * 16 + (l & 15);
        *(u16*)((char*)lP[w] + prow * 128 + ((col * 2) ^ ((prow & 7) << 4))) =
            f2bf(p);
      }
    }
#pragma unroll
    for (int r = 0; r < 4; ++r) {
      float s = rs[r];
#pragma unroll
      for (int off = 1; off < 16; off <<= 1) s += __shfl_xor(s, off);
      l_i[r] = l_i[r] * corr[r] + s;
    }
#pragma unroll
    for (int g = 0; g < 2; ++g)
#pragma unroll
      for (int r = 0; r < 4; ++r) acc_o[g][r] *= corr[r];

    // PV: P [16 rows][64 j] x Vt [32 dh][64 j]
#pragma unroll
    for (int kp = 0; kp < 2; ++kp) {
      int prow = l & 15;
      int koff = (((l >> 4) << 4) + kp * 64) ^ ((prow & 7) << 4);
      bf16x8 pf = *(const bf16x8*)((const char*)lP[w] + prow * 128 + koff);
#pragma unroll
      for (int g = 0; g < 2; ++g) {
        int vrow = g * 16 + (l & 15);
        int vkoff = (((l >> 4) << 4) + kp * 64) ^ ((vrow & 7) << 4);
        bf16x8 vf = *(const bf16x8*)((const char*)lV + vrow * 128 + vkoff);
        acc_o[g] = __builtin_amdgcn_mfma_f32_16x16x32_bf16(pf, vf, acc_o[g], 0, 0, 0);
      }
    }
    __syncthreads();
  }

  // epilogue: normalize, gate, store bf16 to ao[b*S+s][h*32+dh]
#pragma unroll
  for (int g = 0; g < 2; ++g)
#pragma unroll
    for (int r = 0; r < 4; ++r) {
      int rr = rowr[r];
      int dh = g * 16 + (l & 15);
      float gate = gates[(size_t)(b * S_ + rr) * 256 + h * 32 + dh];
      float o = acc_o[g][r] / l_i[r] * gate;
      ao[(size_t)(b * S_ + rr) * 256 + h * 32 + dh] = f2bf(o);
    }
}

// ---------------- kernel 5: out = ao @ Wo^T + bo ----------------
__global__ __launch_bounds__(256) void gemm_out(const u16* __restrict__ ao,
                                                const u16* __restrict__ wot,
                                                const float* __restrict__ bo,
                                                float* __restrict__ out) {
  __shared__ u16 lA[128 * 32];
  __shared__ u16 lB[128 * 32];
  const int tid = threadIdx.x, l = tid & 63, w = tid >> 6;
  const int m0 = blockIdx.x * 128, n0 = blockIdx.y * 128;
  const int wm = w >> 1, wn = w & 1;
  f32x4 acc[4][4];
#pragma unroll
  for (int i = 0; i < 4; ++i)
#pragma unroll
    for (int j = 0; j < 4; ++j) acc[i][j] = (f32x4){0.f, 0.f, 0.f, 0.f};

  for (int ks = 0; ks < 8; ++ks) {
#pragma unroll
    for (int i = 0; i < 2; ++i) {
      int slot = i * 256 + tid;
      int row = slot >> 2, sk = slot & 3;
      int sw = sk ^ ((row >> 1) & 3);
      gload_lds16(ao + (size_t)(m0 + row) * 256 + ks * 32 + sw * 8,
                  (char*)lA + slot * 16);
    }
#pragma unroll
    for (int i = 0; i < 2; ++i) {
      int slot = i * 256 + tid;
      int row = slot >> 2, sk = slot & 3;
      int sw = sk ^ ((row >> 1) & 3);
      gload_lds16(wot + (size_t)(n0 + row) * 256 + ks * 32 + sw * 8,
                  (char*)lB + slot * 16);
    }
    __syncthreads();
    bf16x8 af[4], bfr[4];
#pragma unroll
    for (int mi = 0; mi < 4; ++mi) {
      int row = wm * 64 + mi * 16 + (l & 15);
      int koff = ((l >> 4) << 4) ^ (((row >> 1) & 3) << 4);
      af[mi] = *(const bf16x8*)((const char*)lA + row * 64 + koff);
    }
#pragma unroll
    for (int ni = 0; ni < 4; ++ni) {
      int row = wn * 64 + ni * 16 + (l & 15);
      int koff = ((l >> 4) << 4) ^ (((row >> 1) & 3) << 4);
      bfr[ni] = *(const bf16x8*)((const char*)lB + row * 64 + koff);
    }
#pragma unroll
    for (int mi = 0; mi < 4; ++mi)
#pragma unroll
      for (int ni = 0; ni < 4; ++ni)
        acc[mi][ni] = __builtin_amdgcn_mfma_f32_16x16x32_bf16(
            af[mi], bfr[ni], acc[mi][ni], 0, 0, 0);
    __syncthreads();
  }
#pragma unroll
  for (int mi = 0; mi < 4; ++mi)
#pragma unroll
    for (int ni = 0; ni < 4; ++ni) {
      int row = m0 + wm * 64 + mi * 16 + ((l >> 4) << 2);
      int col = n0 + wn * 64 + ni * 16 + (l & 15);
#pragma unroll
      for (int r = 0; r < 4; ++r)
        out[(size_t)(row + r) * 256 + col] = acc[mi][ni][r] + bo[col];
    }
}

extern "C" void kernel_launch(void* const* d_in, const int* in_sizes, int n_in,
                              void* d_out, int out_size, void* d_ws,
                              size_t ws_size, hipStream_t stream) {
  const float* x   = (const float*)d_in[0];
  const int* mask  = (const int*)d_in[1];
  const float* bias = (const float*)d_in[2];
  const float* Wq  = (const float*)d_in[3];
  const float* Wkv = (const float*)d_in[4];
  const float* Wo  = (const float*)d_in[5];
  const float* bo  = (const float*)d_in[6];
  const float* Wg  = (const float*)d_in[7];
  const float* bg  = (const float*)d_in[8];

  char* ws = (char*)d_ws;
  u16* xb      = (u16*)(ws);                 // 2 MB   [4096][256] bf16
  u16* wt      = (u16*)(ws + 2097152);       // 512 KB [1024][256] bf16
  u16* wot     = (u16*)(ws + 2621440);       // 128 KB [256][256] bf16
  u16* qs      = (u16*)(ws + 2752512);       // 2 MB   [b][h][s][dh] bf16 (q*scale)
  u16* kb      = (u16*)(ws + 4849664);       // 2 MB   [b][h][s][dh] bf16
  u16* vt      = (u16*)(ws + 6946816);       // 2 MB   [b][h][dh][s] bf16
  float* gates = (float*)(ws + 9043968);     // 4 MB   [4096][256] f32
  u16* ao      = (u16*)(ws + 13238272);      // 2 MB   [4096][256] bf16 (gated)
  float* out   = (float*)d_out;

  conv_x<<<dim3(1024), dim3(256), 0, stream>>>(x, xb);
  prep_w<<<dim3(1280), dim3(256), 0, stream>>>(Wq, Wkv, Wo, Wg, wt, wot);
  gemm_proj<<<dim3(32, 8), dim3(256), 0, stream>>>(xb, wt, bg, qs, kb, vt, gates);
  attn_fwd<<<dim3(32, 8, 2), dim3(256), 0, stream>>>(qs, kb, vt, bias, mask, gates, ao);
  gemm_out<<<dim3(32, 2), dim3(256), 0, stream>>>(ao, wot, bo, out);
}